// Round 1
// baseline (244.289 us; speedup 1.0000x reference)
//
#include <hip/hip_runtime.h>

// TTTConv: fused RMSNorm + depthwise causal conv1d (K=4), f32 in / f32 out.
// B=4, S=4096, H=2048. Memory-bound: goal = read x once, write out once.

#define BQ 4
#define SQ 4096
#define HQ 2048
#define KQ 4
#define TROWS 32            // s-rows of output per block
#define NTHREADS 512        // 512 thr * float4 = 2048 = H (one full row/iter)
#define NWAVES (NTHREADS / 64)

__global__ __launch_bounds__(NTHREADS, 2) void ttt_conv_kernel(
    const float* __restrict__ x,    // [B,S,H]
    const float* __restrict__ nw,   // [H]
    const float* __restrict__ cw,   // [H,1,K]
    const float* __restrict__ cb,   // [H]
    float* __restrict__ out)        // [B,S,H]
{
    __shared__ float part[2][NWAVES];   // double-buffered wave partials

    const int tid  = threadIdx.x;
    const int lane = tid & 63;
    const int wid  = tid >> 6;

    const int tilesPerB = SQ / TROWS;
    const int b  = blockIdx.x / tilesPerB;
    const int s0 = (blockIdx.x % tilesPerB) * TROWS;
    const int h4 = tid * 4;

    // per-thread constants
    const float4 w4    = *reinterpret_cast<const float4*>(nw + h4);
    const float4 bias4 = *reinterpret_cast<const float4*>(cb + h4);
    // conv_weight [H,1,K]: (h,k) at h*K+k. K=4 -> one float4 per h.
    const float4 r0 = *reinterpret_cast<const float4*>(cw + (size_t)(h4 + 0) * KQ);
    const float4 r1 = *reinterpret_cast<const float4*>(cw + (size_t)(h4 + 1) * KQ);
    const float4 r2 = *reinterpret_cast<const float4*>(cw + (size_t)(h4 + 2) * KQ);
    const float4 r3 = *reinterpret_cast<const float4*>(cw + (size_t)(h4 + 3) * KQ);
    // transpose: cwk[k] = tap k for the 4 owned channels
    const float4 cw0 = make_float4(r0.x, r1.x, r2.x, r3.x);
    const float4 cw1 = make_float4(r0.y, r1.y, r2.y, r3.y);
    const float4 cw2 = make_float4(r0.z, r1.z, r2.z, r3.z);
    const float4 cw3 = make_float4(r0.w, r1.w, r2.w, r3.w);

    const float* xb = x   + (size_t)b * SQ * HQ + h4;
    float*       ob = out + (size_t)b * SQ * HQ + h4;

    float4 win0 = make_float4(0, 0, 0, 0);
    float4 win1 = make_float4(0, 0, 0, 0);
    float4 win2 = make_float4(0, 0, 0, 0);
    float4 win3 = make_float4(0, 0, 0, 0);

    const int sEnd = s0 + TROWS;
    int s = s0 - (KQ - 1);

    float4 xv_next = make_float4(0, 0, 0, 0);
    if (s >= 0) xv_next = *reinterpret_cast<const float4*>(xb + (size_t)s * HQ);

    int parity = 0;
    for (; s < sEnd; ++s) {
        const float4 xv = xv_next;
        const int sn = s + 1;
        if (sn < sEnd) {
            // issue next row's load BEFORE the barrier -> HBM latency hides
            xv_next = (sn >= 0)
                ? *reinterpret_cast<const float4*>(xb + (size_t)sn * HQ)
                : make_float4(0, 0, 0, 0);
        }

        // ---- block-wide sum of squares for row s ----
        float p = xv.x * xv.x + xv.y * xv.y + xv.z * xv.z + xv.w * xv.w;
        #pragma unroll
        for (int off = 32; off >= 1; off >>= 1)
            p += __shfl_xor(p, off, 64);
        if (lane == 0) part[parity][wid] = p;
        __syncthreads();
        float tot = 0.f;
        #pragma unroll
        for (int wv = 0; wv < NWAVES; ++wv) tot += part[parity][wv];
        parity ^= 1;

        const float scale = rsqrtf(tot * (1.0f / HQ) + 1e-6f);

        // normalized row (zero rows stay zero: xv==0 -> xn==0)
        float4 xn;
        xn.x = xv.x * scale * w4.x;
        xn.y = xv.y * scale * w4.y;
        xn.z = xv.z * scale * w4.z;
        xn.w = xv.w * scale * w4.w;

        // slide window: win0 oldest (s-3) ... win3 = s
        win0 = win1; win1 = win2; win2 = win3; win3 = xn;

        if (s >= s0) {
            float4 o;
            o.x = bias4.x + cw0.x * win0.x + cw1.x * win1.x + cw2.x * win2.x + cw3.x * win3.x;
            o.y = bias4.y + cw0.y * win0.y + cw1.y * win1.y + cw2.y * win2.y + cw3.y * win3.y;
            o.z = bias4.z + cw0.z * win0.z + cw1.z * win1.z + cw2.z * win2.z + cw3.z * win3.z;
            o.w = bias4.w + cw0.w * win0.w + cw1.w * win1.w + cw2.w * win2.w + cw3.w * win3.w;
            *reinterpret_cast<float4*>(ob + (size_t)s * HQ) = o;
        }
    }
}

extern "C" void kernel_launch(void* const* d_in, const int* in_sizes, int n_in,
                              void* d_out, int out_size, void* d_ws, size_t ws_size,
                              hipStream_t stream) {
    const float* x  = (const float*)d_in[0];  // hidden_states [B,S,H] f32
    const float* nw = (const float*)d_in[1];  // norm_weight [H] f32
    const float* cw = (const float*)d_in[2];  // conv_weight [H,1,K] f32
    const float* cb = (const float*)d_in[3];  // conv_bias [H] f32
    float* o = (float*)d_out;

    const int grid = BQ * (SQ / TROWS);       // 4 * 128 = 512 blocks
    ttt_conv_kernel<<<grid, NTHREADS, 0, stream>>>(x, nw, cw, cb, o);
}

// Round 3
// 241.842 us; speedup vs baseline: 1.0101x; 1.0101x over previous
//
#include <hip/hip_runtime.h>

// TTTConv: fused RMSNorm + depthwise causal conv1d (K=4), f32 in / f32 out.
// B=4, S=4096, H=2048. Memory-bound. R1: batch 4 rows per barrier to get
// 64 B/thread in flight (was 16 B) and 4x fewer sync round trips.
// R2: fix nontemporal store (needs native vector type, not HIP float4 class).

#define BQ 4
#define SQ 4096
#define HQ 2048
#define KQ 4
#define TROWS 32            // output s-rows per block
#define RB 4                // rows per barrier group
#define NGRP (TROWS / RB + 1)   // 9 groups: group 0 = halo rows s0-4..s0-1
#define NTHREADS 512        // 512 thr * float4 = 2048 = H (one full row/iter)
#define NWAVES (NTHREADS / 64)

typedef float f32x4 __attribute__((ext_vector_type(4)));

__global__ __launch_bounds__(NTHREADS, 4) void ttt_conv_kernel(
    const float* __restrict__ x,      // [B,S,H]
    const float* __restrict__ gamma,  // [H] norm weight
    const float* __restrict__ cwp,    // [H,1,K]
    const float* __restrict__ cbp,    // [H]
    float* __restrict__ out)          // [B,S,H]
{
    __shared__ float part[2][RB][NWAVES];   // parity-double-buffered partials

    const int tid  = threadIdx.x;
    const int lane = tid & 63;
    const int wid  = tid >> 6;

    const int tilesPerB = SQ / TROWS;
    const int b  = blockIdx.x / tilesPerB;
    const int s0 = (blockIdx.x % tilesPerB) * TROWS;
    const int h4 = tid * 4;

    const float4 g4    = *reinterpret_cast<const float4*>(gamma + h4);
    const float4 bias4 = *reinterpret_cast<const float4*>(cbp + h4);
    // conv_weight [H,1,K], K=4 -> one float4 per channel; transpose to taps.
    const float4 r0 = *reinterpret_cast<const float4*>(cwp + (size_t)(h4 + 0) * KQ);
    const float4 r1 = *reinterpret_cast<const float4*>(cwp + (size_t)(h4 + 1) * KQ);
    const float4 r2 = *reinterpret_cast<const float4*>(cwp + (size_t)(h4 + 2) * KQ);
    const float4 r3 = *reinterpret_cast<const float4*>(cwp + (size_t)(h4 + 3) * KQ);
    const float4 c0 = make_float4(r0.x, r1.x, r2.x, r3.x);  // tap k=0 (s-3)
    const float4 c1 = make_float4(r0.y, r1.y, r2.y, r3.y);  // tap k=1 (s-2)
    const float4 c2 = make_float4(r0.z, r1.z, r2.z, r3.z);  // tap k=2 (s-1)
    const float4 c3 = make_float4(r0.w, r1.w, r2.w, r3.w);  // tap k=3 (s)

    const float* xb = x   + (size_t)b * SQ * HQ + h4;
    float*       ob = out + (size_t)b * SQ * HQ + h4;

    const float4 f4z = make_float4(0.f, 0.f, 0.f, 0.f);
    // normalized window: wm3 = row s-3 (oldest), wm2 = s-2, wm1 = s-1
    float4 wm3 = f4z, wm2 = f4z, wm1 = f4z;

    float4 buf[RB];
    // prefetch group 0: rows s0-4 .. s0-1 (halo; row s0-4 is discarded)
    {
        const int base = s0 - RB;
        #pragma unroll
        for (int r = 0; r < RB; ++r) {
            const int s = base + r;
            buf[r] = (s >= 0) ? *reinterpret_cast<const float4*>(xb + (size_t)s * HQ)
                              : f4z;
        }
    }

    for (int g = 0; g < NGRP; ++g) {
        const int base = s0 - RB + g * RB;

        float4 cur[RB];
        #pragma unroll
        for (int r = 0; r < RB; ++r) cur[r] = buf[r];

        // sum of squares partials (consumes cur -> frees buf for prefetch)
        float p[RB];
        #pragma unroll
        for (int r = 0; r < RB; ++r)
            p[r] = cur[r].x * cur[r].x + cur[r].y * cur[r].y
                 + cur[r].z * cur[r].z + cur[r].w * cur[r].w;

        // prefetch next group NOW: HBM latency hides under shfl chain + barrier
        if (g + 1 < NGRP) {
            const int nb = base + RB;
            #pragma unroll
            for (int r = 0; r < RB; ++r) {
                const int s = nb + r;
                buf[r] = (s >= 0) ? *reinterpret_cast<const float4*>(xb + (size_t)s * HQ)
                                  : f4z;
            }
        }

        // 4 independent 6-step wave reductions (pipeline, no serial chain x4)
        #pragma unroll
        for (int off = 32; off >= 1; off >>= 1) {
            #pragma unroll
            for (int r = 0; r < RB; ++r)
                p[r] += __shfl_xor(p[r], off, 64);
        }
        if (lane == 0) {
            #pragma unroll
            for (int r = 0; r < RB; ++r) part[g & 1][r][wid] = p[r];
        }
        __syncthreads();

        float tot[RB];
        #pragma unroll
        for (int r = 0; r < RB; ++r) {
            const float4 pa = *reinterpret_cast<const float4*>(&part[g & 1][r][0]);
            const float4 pb = *reinterpret_cast<const float4*>(&part[g & 1][r][4]);
            tot[r] = (pa.x + pa.y + pa.z + pa.w) + (pb.x + pb.y + pb.z + pb.w);
        }

        #pragma unroll
        for (int r = 0; r < RB; ++r) {
            const float scale = rsqrtf(tot[r] * (1.0f / HQ) + 1e-6f);
            float4 xn;
            xn.x = cur[r].x * scale * g4.x;
            xn.y = cur[r].y * scale * g4.y;
            xn.z = cur[r].z * scale * g4.z;
            xn.w = cur[r].w * scale * g4.w;

            if (g > 0) {   // uniform branch: groups 1..8 emit outputs
                f32x4 o;
                o.x = bias4.x + c0.x * wm3.x + c1.x * wm2.x + c2.x * wm1.x + c3.x * xn.x;
                o.y = bias4.y + c0.y * wm3.y + c1.y * wm2.y + c2.y * wm1.y + c3.y * xn.y;
                o.z = bias4.z + c0.z * wm3.z + c1.z * wm2.z + c2.z * wm1.z + c3.z * xn.z;
                o.w = bias4.w + c0.w * wm3.w + c1.w * wm2.w + c2.w * wm1.w + c3.w * xn.w;
                const int s = base + r;
                __builtin_nontemporal_store(
                    o, reinterpret_cast<f32x4*>(ob + (size_t)s * HQ));
            }
            wm3 = wm2; wm2 = wm1; wm1 = xn;
        }
    }
}

extern "C" void kernel_launch(void* const* d_in, const int* in_sizes, int n_in,
                              void* d_out, int out_size, void* d_ws, size_t ws_size,
                              hipStream_t stream) {
    const float* x  = (const float*)d_in[0];  // hidden_states [B,S,H] f32
    const float* nw = (const float*)d_in[1];  // norm_weight [H] f32
    const float* cw = (const float*)d_in[2];  // conv_weight [H,1,K] f32
    const float* cb = (const float*)d_in[3];  // conv_bias [H] f32
    float* o = (float*)d_out;

    const int grid = BQ * (SQ / TROWS);       // 4 * 128 = 512 blocks, 2/CU
    ttt_conv_kernel<<<grid, NTHREADS, 0, stream>>>(x, nw, cw, cb, o);
}